// Round 9
// baseline (86.768 us; speedup 1.0000x reference)
//
#include <hip/hip_runtime.h>

// TanhAttention: B=4, L=512, D=256
//   scores[b,i,j] = sum_d tanh(H[b,i,d]+H[b,j,d]) * w[d] + bias
//   alpha = softmax_j(scores); r = alpha @ H
// Outputs concatenated: r (524288 floats) then alpha (1048576 floats).
//
// Math: tanh(x) = 1 - 2/(1+e^{2x}); with E = exp2(K*h), K = 2*log2(e):
//   e^{2(hi+hj)} = Ei*Ej  ->  score_shifted = -2*sum_d w_d * rcp(fma(Ei,Ej,1))
// (softmax shift cancels sum(w)+bias -> bias unused; symmetric -> upper tiles only).
//
// Ladder: R13 8-wave score; R14 T2 waves x2 -> 0; R15 w->SGPR -> +1.9 (rev);
//   R16 attribution: score+gap=17.8; R17 T2 rows 8 -> -1.6 (L2 floor);
//   R18 512-block persistent -> +5.2 (cut 3->2 blocks/CU; TLP-sensitive!);
//   R19 wlds+pin -> -0.8 (85.2); R20 ticket fusion -> +70 (XCD coherence
//   catastrophe, fusion dead); R21 direct-mirror epilogue -> -0.3 (84.9).
// R22: score occupancy via LDS diet. R20 evidence: VGPR~40 => score was LDS-
//   bound (46.6KB -> 3 blocks/CU). Trans floor ~8us vs measured ~13 => 55%
//   trans util, bubbles = staging/epilogue; fill with TLP. (a) ST=36 pad ->
//   rotation swizzle r*32+((4q+4r)&31): 36.9->32KB, bank-neutral (reads all-32-
//   banks: 4R&31=4ig for both ii; writes same min-8-phase as ST=36). (b) pr
//   aliased into own wave's staging (rows dead post-q-loop; wave-local WAR
//   ordered by data dep; cross-wave after syncthreads) with (col+row)&15
//   rotation. LDS 33.75KB -> 4 blocks/CU, __launch_bounds__(512,8).
//   Predict T_score 13 -> ~10-11: dur 84.9 -> ~81.5-83.

#define B_ 4
#define L_ 512
#define D_ 256
#define NT16 32         // L_/16
#define NTRI16 528      // 32*33/2 upper-tri 16x16 tiles per batch

typedef float v4f __attribute__((ext_vector_type(4)));

__global__ __launch_bounds__(512, 8) void score_kernel(
    const float* __restrict__ H, const float* __restrict__ w,
    float* __restrict__ sOut)
{
    // Per-wave 1024-dword region: swizzled E staging (32 rows x 32 d).
    // After the q-loop, first 256 dwords are reused as this wave's pr tile.
    __shared__ __align__(16) float lds[8][1024];      // 32 KB
    __shared__ __align__(16) float wlds[8][32];       // 1 KB per-wave w slices

    const int tid  = threadIdx.x;
    const int wv   = tid >> 6;               // D-slice index 0..7
    const int lane = tid & 63;
    const int blk  = blockIdx.x;             // 0 .. 2111 (one block per (b,tile))
    const int b    = blk / NTRI16;
    const int t    = blk - b * NTRI16;
    // closed-form upper-tri index: n = 32-ti solves n(n+1)/2 >= u, u = 528-t
    const int u  = NTRI16 - t;
    int n = (int)((__builtin_amdgcn_sqrtf((float)(8 * u + 1)) - 1.0f) * 0.5f);
    while (n * (n + 1) / 2 < u) ++n;         // fp fixup, <=2 iters
    const int ti = NT16 - n;
    const int tj = ti + (t - (NTRI16 - n * (n + 1) / 2));
    const int i0 = ti * 16, j0 = tj * 16;
    const int dq0 = wv * 32;                 // this wave's 32-d slice
    const float K = 2.8853900817779268f;     // 2*log2(e)
    const float* Hb = H + (size_t)b * L_ * D_;

    const int ig = lane >> 3, jg = lane & 7; // i = i0+ig+8*ii, j = j0+jg+8*jj

    float* const buf = &lds[wv][0];

    // w slice -> this wave's LDS (wave-local: wave_barrier suffices)
    if (lane < 32) wlds[wv][lane] = w[dq0 + lane];

    // ---- stage this wave's 32 rows x 32 d: 256 quads / 64 lanes = 4 each ----
    // Swizzled: dword offset = r*32 + ((4q + 4r) & 31)  (no padding)
    float4 hv[4];
    int soff[4];
    #pragma unroll
    for (int s = 0; s < 4; ++s) {
        int idx = lane + 64 * s;
        int r = idx >> 3, q = idx & 7;
        int srow = (r < 16) ? (i0 + r) : (j0 + r - 16);
        soff[s] = (r << 5) + ((4 * q + 4 * r) & 31);
        hv[s] = *(const float4*)(Hb + srow * D_ + dq0 + 4 * q);   // batched loads
    }
    #pragma unroll
    for (int s = 0; s < 4; ++s) {
        v4f ev;
        ev.x = __builtin_amdgcn_exp2f(hv[s].x * K);
        ev.y = __builtin_amdgcn_exp2f(hv[s].y * K);
        ev.z = __builtin_amdgcn_exp2f(hv[s].z * K);
        ev.w = __builtin_amdgcn_exp2f(hv[s].w * K);
        *(v4f*)&buf[soff[s]] = ev;
    }

    __builtin_amdgcn_wave_barrier();         // pin ds_writes before reads (own wave only)

    v4f acc[2][2];
    #pragma unroll
    for (int ii = 0; ii < 2; ++ii)
        #pragma unroll
        for (int jj = 0; jj < 2; ++jj) acc[ii][jj] = (v4f){0.f, 0.f, 0.f, 0.f};

    #pragma unroll
    for (int q = 0; q < 8; ++q) {            // 4-d block per step
        v4f wvv = *(const v4f*)&wlds[wv][4 * q];   // uniform-address broadcast read
        // 4R&31 is identical for ii=0/1 (R=ig, 8+ig) and jj=0/1 (R=16+jg, 24+jg)
        const int ci = (4 * q + 4 * ig) & 31;
        const int cj = (4 * q + 4 * jg) & 31;
        v4f Ei[2], Ej[2];
        Ei[0] = *(const v4f*)&buf[(ig << 5) + ci];
        Ei[1] = *(const v4f*)&buf[((8 + ig) << 5) + ci];
        Ej[0] = *(const v4f*)&buf[((16 + jg) << 5) + cj];
        Ej[1] = *(const v4f*)&buf[((24 + jg) << 5) + cj];
        #pragma unroll
        for (int ii = 0; ii < 2; ++ii)
            #pragma unroll
            for (int jj = 0; jj < 2; ++jj) {
                v4f den = Ei[ii] * Ej[jj] + 1.0f;
                v4f rr;
                rr.x = __builtin_amdgcn_rcpf(den.x);
                rr.y = __builtin_amdgcn_rcpf(den.y);
                rr.z = __builtin_amdgcn_rcpf(den.z);
                rr.w = __builtin_amdgcn_rcpf(den.w);
                acc[ii][jj] += wvv * rr;
            }
    }

    // ---- partials into own staging region (rows dead; data-dep orders WAR) ----
    // pr[wv][row][col] @ lds[wv][row*16 + ((col+row)&15)]
    #pragma unroll
    for (int ii = 0; ii < 2; ++ii)
        #pragma unroll
        for (int jj = 0; jj < 2; ++jj) {
            v4f a = acc[ii][jj];
            const int row = ig + 8 * ii, col = jg + 8 * jj;
            buf[row * 16 + ((col + row) & 15)] = a.x + a.y + a.z + a.w;
        }
    __syncthreads();

    // ---- combine: all 512 threads; lower half = upper tile, upper half = mirror.
    // Diagonal tiles: both halves write the same location with bit-identical
    // values (same staged E slots, commutative mul, same k reduction order).
    {
        const int row = (tid >> 4) & 15, col = tid & 15;
        if (tid < 256) {
            float val = 0.0f;
            #pragma unroll
            for (int k = 0; k < 8; ++k)
                val += lds[k][row * 16 + ((col + row) & 15)];
            val *= -2.0f;                    // shifted score
            sOut[((size_t)b * L_ + i0 + row) * L_ + j0 + col] = val;
        } else {
            float val = 0.0f;                // mirror: tile[col][row] at (j0+row, i0+col)
            #pragma unroll
            for (int k = 0; k < 8; ++k)
                val += lds[k][col * 16 + ((row + col) & 15)];
            val *= -2.0f;
            sOut[((size_t)b * L_ + j0 + row) * L_ + i0 + col] = val;
        }
    }
}

// Phase 2 (R17, near L2-BW floor): 256 blocks x 512 thr (8 waves); 8 rows/block.
// A: softmax, wave w owns row w. B: r-phase, wave w owns j in [64w,64w+64),
// racc[8]; H[b] once per block (128MB L2 total). C: union'd pr reduce.
union SMem {
    float sc[8][L_];          // 16 KB (phases A,B)
    float pr[8][8][D_];       // 64 KB (phase C)
};

__global__ __launch_bounds__(512) void softmax_r_kernel(
    const float* __restrict__ H, float* __restrict__ rOut, float* __restrict__ aOut)
{
    __shared__ __align__(16) SMem u;

    const int tid  = threadIdx.x;
    const int blk  = blockIdx.x;     // 0..255
    const int b    = blk >> 6;
    const int i0   = (blk & 63) * 8;
    const int wv   = tid >> 6;       // wave 0..7
    const int lane = tid & 63;
    const float* Hb = H + (size_t)b * L_ * D_;
    const float L2E = 1.4426950408889634f;

    // ---- A: softmax, wave wv handles row wv ----
    {
        const int row = wv;
        float* aRow = aOut + ((size_t)b * L_ + i0 + row) * L_;
        float v[8];
        float m = -1e30f;
        #pragma unroll
        for (int k = 0; k < 8; ++k) {
            v[k] = aRow[lane + 64 * k];      // coalesced score reads (L2/L3-hot)
            m = fmaxf(m, v[k]);
        }
        #pragma unroll
        for (int off = 1; off < 64; off <<= 1)
            m = fmaxf(m, __shfl_xor(m, off, 64));
        float s = 0.0f;
        #pragma unroll
        for (int k = 0; k < 8; ++k) {
            v[k] = __builtin_amdgcn_exp2f((v[k] - m) * L2E);
            s += v[k];
        }
        #pragma unroll
        for (int off = 1; off < 64; off <<= 1)
            s += __shfl_xor(s, off, 64);
        const float inv = __builtin_amdgcn_rcpf(s);
        #pragma unroll
        for (int k = 0; k < 8; ++k) {
            float a = v[k] * inv;
            u.sc[row][lane + 64 * k] = a;
            aRow[lane + 64 * k] = a;         // overwrite scores with alpha in place
        }
    }
    __syncthreads();

    // ---- B: r-phase, wave-cooperative over j (64 j per wave), 8 rows ----
    const int jbase = 64 * wv;
    v4f racc[8];
    #pragma unroll
    for (int r = 0; r < 8; ++r) racc[r] = (v4f){0.f, 0.f, 0.f, 0.f};
    const v4f* Hb4 = (const v4f*)Hb;         // [512][64]

    #pragma unroll 2
    for (int js = 0; js < 64; js += 4) {
        v4f h[4];
        #pragma unroll
        for (int q = 0; q < 4; ++q)
            h[q] = Hb4[(size_t)(jbase + js + q) * (D_ / 4) + lane];
        #pragma unroll
        for (int r = 0; r < 8; ++r) {
            v4f av = *(const v4f*)&u.sc[r][jbase + js];   // b128 uniform broadcast
            #pragma unroll
            for (int q = 0; q < 4; ++q)
                racc[r] += av[q] * h[q];
        }
    }
    __syncthreads();                 // all sc reads done before pr overwrites it

    #pragma unroll
    for (int r = 0; r < 8; ++r)
        *(v4f*)&u.pr[wv][r][4 * lane] = racc[r];
    __syncthreads();

    // ---- C: reduce 8 wave-partials, write r (all 512 threads) ----
    {
        const int fq  = tid & 63;        // float4 index in D
        const int row = tid >> 6;        // 0..7
        v4f s = *(const v4f*)&u.pr[0][row][4 * fq];
        #pragma unroll
        for (int k = 1; k < 8; ++k)
            s += *(const v4f*)&u.pr[k][row][4 * fq];
        *(v4f*)&rOut[((size_t)b * L_ + i0 + row) * D_ + 4 * fq] = s;
    }
}

extern "C" void kernel_launch(void* const* d_in, const int* in_sizes, int n_in,
                              void* d_out, int out_size, void* d_ws, size_t ws_size,
                              hipStream_t stream) {
    const float* H = (const float*)d_in[0];
    const float* w = (const float*)d_in[1];
    // d_in[2] (bias) unused: softmax shift-invariance cancels it.
    float* rOut = (float*)d_out;
    float* aOut = rOut + (size_t)B_ * L_ * D_;   // alpha region doubles as score scratch

    score_kernel<<<dim3(B_ * NTRI16), 512, 0, stream>>>(H, w, aOut);
    softmax_r_kernel<<<dim3(B_ * (L_ / 8)), 512, 0, stream>>>(H, rOut, aOut);
}